// Round 3
// baseline (74.286 us; speedup 1.0000x reference)
//
#include <hip/hip_runtime.h>

#define SMOOTHF 0.001f
#define DICE_WF 0.8f

constexpr int N_B = 16, N_C = 3, N_H = 512, N_W = 512;
constexpr int SLICES    = N_B * N_C;          // 48
constexpr int ELEMS     = N_H * N_W;          // 262144 elements per (b,c) slice
constexpr int TPB       = 256;
constexpr int BPS       = 32;                 // blocks per slice
constexpr int NBLK      = SLICES * BPS;       // 1536 blocks
constexpr int V4_SLICE  = ELEMS / 4;          // 65536 float4 per slice
constexpr int V4_BLOCK  = V4_SLICE / BPS;     // 2048 float4 per block
constexpr int V4_THREAD = V4_BLOCK / TPB;     // 8 float4 per thread
constexpr int WS_FLOATS = 5 * NBLK;           // SoA partials: ws[comp][NBLK]
// ticket counter lives right after the partials (30720 B, 16-aligned)

// Five linear accumulators (targets are exactly {0,1}):
//   sp = Σ sigmoid(x)   pt = Σ sigmoid(x)·t   st = Σ t
//   sd = Σ (x−t)²       sdt = Σ (x−t)²·t
// inter = pt, cnt_pos = st, sse_pos = sdt, sse_neg = sd − sdt.
struct Acc { float sp, pt, st, sd, sdt; };

__device__ __forceinline__ void acc1(float x, float t, Acc& a) {
    float e  = __expf(-x);
    float p  = __builtin_amdgcn_rcpf(1.0f + e);  // sigmoid via v_rcp
    float d  = x - t;
    float d2 = d * d;
    a.sp += p;
    a.pt  = fmaf(p, t, a.pt);
    a.st += t;
    a.sd += d2;
    a.sdt = fmaf(d2, t, a.sdt);
}

__device__ __forceinline__ void waveReduce5(Acc& a) {
    #pragma unroll
    for (int off = 32; off > 0; off >>= 1) {
        a.sp  += __shfl_down(a.sp,  off, 64);
        a.pt  += __shfl_down(a.pt,  off, 64);
        a.st  += __shfl_down(a.st,  off, 64);
        a.sd  += __shfl_down(a.sd,  off, 64);
        a.sdt += __shfl_down(a.sdt, off, 64);
    }
}

// Single-pass: every block reduces its chunk and deposits 5 partials; the
// block taking the LAST ticket performs the (deterministic, fixed-order)
// final reduction in-kernel. Counter is zeroed by a memset node each call.
__global__ __launch_bounds__(TPB) void fused(const float4* __restrict__ lg,
                                             const float4* __restrict__ tg,
                                             float* __restrict__ ws,
                                             unsigned* __restrict__ counter,
                                             float* __restrict__ out) {
    const int blk  = blockIdx.x;
    const int tid  = (int)threadIdx.x;
    const int base = blk * V4_BLOCK + tid;
    Acc a{0.f, 0.f, 0.f, 0.f, 0.f};
    #pragma unroll
    for (int k = 0; k < V4_THREAD; ++k) {
        float4 x4 = lg[base + k * TPB];
        float4 t4 = tg[base + k * TPB];
        acc1(x4.x, t4.x, a); acc1(x4.y, t4.y, a);
        acc1(x4.z, t4.z, a); acc1(x4.w, t4.w, a);
    }
    waveReduce5(a);

    __shared__ float red[TPB / 64][5];
    __shared__ int   s_last;
    const int wave = tid >> 6;
    if ((tid & 63) == 0) {
        red[wave][0] = a.sp; red[wave][1] = a.pt; red[wave][2] = a.st;
        red[wave][3] = a.sd; red[wave][4] = a.sdt;
    }
    __syncthreads();
    if (tid == 0) {
        float v0 = 0.f, v1 = 0.f, v2 = 0.f, v3 = 0.f, v4 = 0.f;
        #pragma unroll
        for (int w = 0; w < TPB / 64; ++w) {
            v0 += red[w][0]; v1 += red[w][1]; v2 += red[w][2];
            v3 += red[w][3]; v4 += red[w][4];
        }
        ws[0 * NBLK + blk] = v0;
        ws[1 * NBLK + blk] = v1;
        ws[2 * NBLK + blk] = v2;
        ws[3 * NBLK + blk] = v3;
        ws[4 * NBLK + blk] = v4;
        __threadfence();                       // release partials (device scope)
        unsigned old = atomicAdd(counter, 1u); // take a ticket
        s_last = (old == (unsigned)(NBLK - 1)) ? 1 : 0;
    }
    __syncthreads();
    if (!s_last) return;

    // ---- finisher: this block saw all NBLK tickets → all partials visible
    __threadfence();                           // acquire

    __shared__ float fin[5][SLICES];
    if (tid < 5 * SLICES) {                    // 240 threads
        const int comp = tid / SLICES;
        const int s    = tid % SLICES;
        const float4* p = (const float4*)(ws + comp * NBLK + s * BPS);
        float4 acc4 = {0.f, 0.f, 0.f, 0.f};
        #pragma unroll
        for (int k = 0; k < BPS / 4; ++k) {
            float4 v = p[k];
            acc4.x += v.x; acc4.y += v.y; acc4.z += v.z; acc4.w += v.w;
        }
        fin[comp][s] = (acc4.x + acc4.y) + (acc4.z + acc4.w);
    }
    __syncthreads();

    __shared__ float dice_s[SLICES], mse_s[SLICES];
    if (tid < SLICES) {
        float sp = fin[0][tid], pt = fin[1][tid], st = fin[2][tid];
        float sd = fin[3][tid], sdt = fin[4][tid];
        dice_s[tid] = (2.0f * pt + SMOOTHF) / (sp + st + SMOOTHF);
        float cp = st, cn = (float)ELEMS - st;
        float s1 = sdt, s0 = sd - sdt;
        float mp = (cp > 0.f) ? s1 / fmaxf(cp, 1.f) : 0.f;
        float mn = (cn > 0.f) ? s0 / fmaxf(cn, 1.f) : 0.f;
        mse_s[tid] = mp + mn;
    }
    __syncthreads();
    if (tid == 0) {
        float dice = 0.f, mse = 0.f;
        #pragma unroll
        for (int s = 0; s < SLICES; ++s) { dice += dice_s[s]; mse += mse_s[s]; }
        float dice_loss = 1.0f - dice / (float)SLICES;   // == Σ_c(1-mean_b)/C
        float mse_loss  = mse / (float)SLICES;           // == Σ/(B·C)
        out[0] = DICE_WF * dice_loss + (1.0f - DICE_WF) * mse_loss;
    }
}

extern "C" void kernel_launch(void* const* d_in, const int* in_sizes, int n_in,
                              void* d_out, int out_size, void* d_ws, size_t ws_size,
                              hipStream_t stream) {
    const float4* lg = (const float4*)d_in[0];
    const float4* tg = (const float4*)d_in[1];
    float* out = (float*)d_out;
    float* ws  = (float*)d_ws;                         // 30 KB partials
    unsigned* counter = (unsigned*)(ws + WS_FLOATS);   // + 4 B ticket counter
    hipMemsetAsync(counter, 0, sizeof(unsigned), stream);  // graph-safe reset
    fused<<<NBLK, TPB, 0, stream>>>(lg, tg, ws, counter, out);
}

// Round 4
// 23.491 us; speedup vs baseline: 3.1623x; 3.1623x over previous
//
#include <hip/hip_runtime.h>

#define SMOOTHF 0.001f
#define DICE_WF 0.8f

constexpr int N_B = 16, N_C = 3, N_H = 512, N_W = 512;
constexpr int SLICES    = N_B * N_C;          // 48
constexpr int ELEMS     = N_H * N_W;          // 262144 elements per (b,c) slice
constexpr int TPB       = 256;
constexpr int BPS       = 32;                 // blocks per slice
constexpr int NBLK      = SLICES * BPS;       // 1536 stage1 blocks
constexpr int V4_SLICE  = ELEMS / 4;          // 65536 float4 per slice
constexpr int V4_BLOCK  = V4_SLICE / BPS;     // 2048 float4 per block
constexpr int V4_THREAD = V4_BLOCK / TPB;     // 8 float4 per thread
constexpr int WS_FLOATS = 5 * NBLK;           // SoA partials: ws[comp][NBLK]

// Five linear accumulators (targets are exactly {0,1}):
//   sp = Σ sigmoid(x)   pt = Σ sigmoid(x)·t   st = Σ t
//   sd = Σ (x−t)²       sdt = Σ (x−t)²·t
// inter = pt, cnt_pos = st, sse_pos = sdt, sse_neg = sd − sdt.
struct Acc { float sp, pt, st, sd, sdt; };

__device__ __forceinline__ void acc1(float x, float t, Acc& a) {
    float e  = __expf(-x);
    float p  = __builtin_amdgcn_rcpf(1.0f + e);  // sigmoid via v_rcp
    float d  = x - t;
    float d2 = d * d;
    a.sp += p;
    a.pt  = fmaf(p, t, a.pt);
    a.st += t;
    a.sd += d2;
    a.sdt = fmaf(d2, t, a.sdt);
}

__device__ __forceinline__ void waveReduce5(Acc& a) {
    #pragma unroll
    for (int off = 32; off > 0; off >>= 1) {
        a.sp  += __shfl_down(a.sp,  off, 64);
        a.pt  += __shfl_down(a.pt,  off, 64);
        a.st  += __shfl_down(a.st,  off, 64);
        a.sd  += __shfl_down(a.sd,  off, 64);
        a.sdt += __shfl_down(a.sdt, off, 64);
    }
}

// Stage 1: block reduces a contiguous 8192-elem chunk of one slice; writes
// 5 partials SoA: ws[c*NBLK + blk]. No fences — kernel boundary orders it.
__global__ __launch_bounds__(TPB) void stage1(const float4* __restrict__ lg,
                                              const float4* __restrict__ tg,
                                              float* __restrict__ ws) {
    const int blk  = blockIdx.x;
    const int tid  = (int)threadIdx.x;
    const int base = blk * V4_BLOCK + tid;
    Acc a{0.f, 0.f, 0.f, 0.f, 0.f};
    #pragma unroll
    for (int k = 0; k < V4_THREAD; ++k) {
        float4 x4 = lg[base + k * TPB];
        float4 t4 = tg[base + k * TPB];
        acc1(x4.x, t4.x, a); acc1(x4.y, t4.y, a);
        acc1(x4.z, t4.z, a); acc1(x4.w, t4.w, a);
    }
    waveReduce5(a);
    __shared__ float red[TPB / 64][5];
    const int wave = tid >> 6;
    if ((tid & 63) == 0) {
        red[wave][0] = a.sp; red[wave][1] = a.pt; red[wave][2] = a.st;
        red[wave][3] = a.sd; red[wave][4] = a.sdt;
    }
    __syncthreads();
    if (tid < 5) {
        float v = 0.f;
        #pragma unroll
        for (int w = 0; w < TPB / 64; ++w) v += red[w][tid];
        ws[tid * NBLK + blk] = v;
    }
}

// Stage 2: one block, 256 threads (finisher-style, fence-free).
// Phase A: 240 threads each fold one (comp, slice) run of 32 contiguous
// floats. Phase B: 48 threads compute per-slice dice/mse. Phase C: serial
// fixed-order 48-add on thread 0 (deterministic).
__global__ __launch_bounds__(TPB) void stage2(const float* __restrict__ ws,
                                              float* __restrict__ out) {
    const int tid = (int)threadIdx.x;
    __shared__ float fin[5][SLICES];
    if (tid < 5 * SLICES) {                    // 240 threads
        const int comp = tid / SLICES;
        const int s    = tid % SLICES;
        const float4* p = (const float4*)(ws + comp * NBLK + s * BPS);
        float4 a4 = {0.f, 0.f, 0.f, 0.f};
        #pragma unroll
        for (int k = 0; k < BPS / 4; ++k) {
            float4 v = p[k];
            a4.x += v.x; a4.y += v.y; a4.z += v.z; a4.w += v.w;
        }
        fin[comp][s] = (a4.x + a4.y) + (a4.z + a4.w);
    }
    __syncthreads();
    __shared__ float dice_s[SLICES], mse_s[SLICES];
    if (tid < SLICES) {
        float sp = fin[0][tid], pt = fin[1][tid], st = fin[2][tid];
        float sd = fin[3][tid], sdt = fin[4][tid];
        dice_s[tid] = (2.0f * pt + SMOOTHF) / (sp + st + SMOOTHF);
        float cp = st, cn = (float)ELEMS - st;
        float s1 = sdt, s0 = sd - sdt;
        float mp = (cp > 0.f) ? s1 / fmaxf(cp, 1.f) : 0.f;
        float mn = (cn > 0.f) ? s0 / fmaxf(cn, 1.f) : 0.f;
        mse_s[tid] = mp + mn;
    }
    __syncthreads();
    if (tid == 0) {
        float dice = 0.f, mse = 0.f;
        #pragma unroll
        for (int s = 0; s < SLICES; ++s) { dice += dice_s[s]; mse += mse_s[s]; }
        float dice_loss = 1.0f - dice / (float)SLICES;   // == Σ_c(1-mean_b)/C
        float mse_loss  = mse / (float)SLICES;           // == Σ/(B·C)
        out[0] = DICE_WF * dice_loss + (1.0f - DICE_WF) * mse_loss;
    }
}

extern "C" void kernel_launch(void* const* d_in, const int* in_sizes, int n_in,
                              void* d_out, int out_size, void* d_ws, size_t ws_size,
                              hipStream_t stream) {
    const float4* lg = (const float4*)d_in[0];
    const float4* tg = (const float4*)d_in[1];
    float* out = (float*)d_out;
    float* ws  = (float*)d_ws;   // 30 KB scratch, fully rewritten each call
    stage1<<<NBLK, TPB, 0, stream>>>(lg, tg, ws);
    stage2<<<1, TPB, 0, stream>>>(ws, out);
}